// Round 6
// baseline (206.759 us; speedup 1.0000x reference)
//
#include <hip/hip_runtime.h>
#include <hip/hip_bf16.h>

#define B_   2
#define N_   2048
#define D_   1024
#define H_   16
#define HD   64
#define HALF 32
#define M_   (B_*N_)     // 4096
#define DQKV (3*D_)      // 3072

typedef __bf16 bf16x8 __attribute__((ext_vector_type(8)));
typedef float  f32x4  __attribute__((ext_vector_type(4)));
typedef float  f32x16 __attribute__((ext_vector_type(16)));

// ---------------------------------------------------------------- swizzled LDS tile helpers
// tile: R rows x 64 bf16 (128B = 8 chunks of 16B per row)
// element (row, col): byte = row*128 + ((col>>3) ^ (row&7))*16 + (col&7)*2
__device__ __forceinline__ bf16x8 ldfrag(const char* tile, int row, int ch) {
    return *(const bf16x8*)(tile + row * 128 + (((ch) ^ (row & 7)) << 4));
}
__device__ __forceinline__ void stfrag16(char* tile, int row, int ch, uint4 v) {
    *(uint4*)(tile + row * 128 + (((ch) ^ (row & 7)) << 4)) = v;
}

__device__ __forceinline__ unsigned pack2(float a, float b) {
    union { __hip_bfloat16 h; unsigned short s; } x, y;
    x.h = __float2bfloat16(a); y.h = __float2bfloat16(b);
    return (unsigned)x.s | ((unsigned)y.s << 16);
}

// ---------------------------------------------------------------- K0: rope tables
__global__ __launch_bounds__(256) void k_tables(float* __restrict__ cos_t,
                                                float* __restrict__ sin_t) {
    int i = blockIdx.x * 256 + threadIdx.x;          // N_*HALF = 65536
    if (i >= N_ * HALF) return;
    int n = i / HALF, j = i % HALF;
    float theta = powf(10000.f, -(float)j / (float)HALF);
    float ang = (float)n * theta;
    cos_t[i] = cosf(ang);
    sin_t[i] = sinf(ang);
}

// ---------------------------------------------------------------- converts
__global__ __launch_bounds__(256) void k_cvt_x(const float* __restrict__ x,
                                               __hip_bfloat16* __restrict__ xb) {
    int i = blockIdx.x * 256 + threadIdx.x;          // over elems/4
    float4 v = ((const float4*)x)[i];
    union { ushort4 u; __hip_bfloat16 h[4]; } o;
    o.h[0] = __float2bfloat16(v.x); o.h[1] = __float2bfloat16(v.y);
    o.h[2] = __float2bfloat16(v.z); o.h[3] = __float2bfloat16(v.w);
    ((ushort4*)xb)[i] = o.u;
}

// transpose+convert: w (1024 x ncols, fp32) -> wt (ncols x 1024, bf16)
__global__ __launch_bounds__(256) void k_cvt_t(const float* __restrict__ w,
                                               __hip_bfloat16* __restrict__ wt, int ncols) {
    __shared__ float tile[32][33];
    int n0 = blockIdx.x * 32, k0 = blockIdx.y * 32;
    int tx = threadIdx.x & 31, ty = threadIdx.x >> 5;   // ty 0..7
#pragma unroll
    for (int i = 0; i < 32; i += 8)
        tile[ty + i][tx] = w[(size_t)(k0 + ty + i) * ncols + n0 + tx];
    __syncthreads();
#pragma unroll
    for (int i = 0; i < 32; i += 8)
        wt[(size_t)(n0 + ty + i) * 1024 + k0 + tx] = __float2bfloat16(tile[tx][ty + i]);
}

// ---------------------------------------------------------------- K1: QKV GEMM (MFMA) + elu+1 + rope
__global__ __launch_bounds__(256) void k_qkv(
        const __hip_bfloat16* __restrict__ xb, const __hip_bfloat16* __restrict__ wqT,
        const float* __restrict__ bias,
        const float* __restrict__ cos_t, const float* __restrict__ sin_t,
        __hip_bfloat16* __restrict__ qf, __hip_bfloat16* __restrict__ kf,
        __hip_bfloat16* __restrict__ rq, __hip_bfloat16* __restrict__ rk,
        __hip_bfloat16* __restrict__ vt) {
    __shared__ __align__(16) char sA[128 * 128];   // 128 rows x 64 bf16
    __shared__ __align__(16) char sB[128 * 128];

    const int t    = threadIdx.x;
    const int m0   = blockIdx.y * 128;
    const int n0w  = blockIdx.x * 128;
    const int lane = t & 63;
    const int lrow = lane & 15;
    const int lgrp = lane >> 4;
    const int wid  = t >> 6;
    const int wr   = wid >> 1;          // wave row 0..1
    const int wc   = wid & 1;           // wave col 0..1

    f32x4 acc[4][4] = {};

    for (int kt = 0; kt < D_ / 64; ++kt) {
        const int k0 = kt * 64;
        __syncthreads();
#pragma unroll
        for (int it = 0; it < 4; ++it) {
            int slot = it * 256 + t;           // 0..1023
            int r = slot >> 3, c = slot & 7;
            uint4 av = *(const uint4*)(xb  + (size_t)(m0  + r) * D_ + k0 + c * 8);
            uint4 bv = *(const uint4*)(wqT + (size_t)(n0w + r) * D_ + k0 + c * 8);
            stfrag16(sA, r, c, av);
            stfrag16(sB, r, c, bv);
        }
        __syncthreads();

        bf16x8 bfr[4][2];
#pragma unroll
        for (int fn = 0; fn < 4; ++fn) {
            bfr[fn][0] = ldfrag(sB, wc * 64 + fn * 16 + lrow, lgrp);
            bfr[fn][1] = ldfrag(sB, wc * 64 + fn * 16 + lrow, 4 + lgrp);
        }
#pragma unroll
        for (int fm = 0; fm < 4; ++fm) {
            bf16x8 a0 = ldfrag(sA, wr * 64 + fm * 16 + lrow, lgrp);
            bf16x8 a1 = ldfrag(sA, wr * 64 + fm * 16 + lrow, 4 + lgrp);
#pragma unroll
            for (int fn = 0; fn < 4; ++fn) {
                acc[fm][fn] = __builtin_amdgcn_mfma_f32_16x16x32_bf16(a0, bfr[fn][0], acc[fm][fn], 0, 0, 0);
                acc[fm][fn] = __builtin_amdgcn_mfma_f32_16x16x32_bf16(a1, bfr[fn][1], acc[fm][fn], 0, 0, 0);
            }
        }
    }

#pragma unroll
    for (int fn = 0; fn < 4; ++fn) {
        int c   = n0w + wc * 64 + fn * 16 + lrow;
        int sec = c >> 10;
        int cc  = c & 1023;
        int h   = cc >> 6, dd = cc & 63;
        float bia = bias[c];
#pragma unroll
        for (int fm = 0; fm < 4; ++fm) {
            int mb = m0 + wr * 64 + fm * 16 + lgrp * 4;
            int b  = mb >> 11;
            int n  = mb & (N_ - 1);
            if (sec == 2) {
                union { ushort4 u; __hip_bfloat16 hh[4]; } pk;
#pragma unroll
                for (int r = 0; r < 4; ++r)
                    pk.hh[r] = __float2bfloat16(acc[fm][fn][r] + bia);
                *(ushort4*)(vt + ((size_t)(b * H_ + h) * HD + dd) * N_ + n) = pk.u;
            } else {
#pragma unroll
                for (int r = 0; r < 4; ++r) {
                    float val = acc[fm][fn][r] + bia;
                    float e  = val > 0.f ? val + 1.f : __expf(val);   // elu(x)+1
                    float ep = __shfl_xor(e, 1);
                    int pj = dd >> 1;
                    float cs = cos_t[(n + r) * HALF + pj];
                    float sn = sin_t[(n + r) * HALF + pj];
                    float rv = (dd & 1) ? (ep * sn + e * cs) : (e * cs - ep * sn);
                    size_t o = ((size_t)(b * H_ + h) * N_ + n + r) * HD + dd;
                    if (sec == 0) { qf[o] = __float2bfloat16(e); rq[o] = __float2bfloat16(rv); }
                    else          { kf[o] = __float2bfloat16(e); rk[o] = __float2bfloat16(rv); }
                }
            }
        }
    }
}

// ---------------------------------------------------------------- K2: fused linear attention
// R4 data path (coalesced reg-stage -> swizzled LDS -> conflict-free frag reads)
// at R5 occupancy (grid 512 = 2 blocks/CU). QBLK=128, 4 q-waves x 32 q-cols.
// Swapped-operand 32x32x16 MFMA, in-register W transform (pack2+permlane32_swap).
// Double-buffered LDS (2x24KB), one barrier per k-tile.
__global__ __launch_bounds__(256, 2) void k_attn(
        const __hip_bfloat16* __restrict__ qf, const __hip_bfloat16* __restrict__ kf,
        const __hip_bfloat16* __restrict__ rq, const __hip_bfloat16* __restrict__ rk,
        const __hip_bfloat16* __restrict__ vt, __hip_bfloat16* __restrict__ ctxb) {
    __shared__ __align__(16) char sbuf[2][3 * 8192];   // per buf: RK | KF | VT

    const int t    = threadIdx.x;
    const int lane = t & 63;
    const int l31  = lane & 31;
    const int h    = lane >> 5;
    const int w    = t >> 6;

    // XCD-chunked swizzle: 512 blocks; XCD x gets bh 4x..4x+3 (K/V ~3MB L2-resident)
    const int bid = blockIdx.x;
    const int swz = (bid & 7) * 64 + (bid >> 3);
    const int bh  = swz >> 4;          // 0..31
    const int q0  = (swz & 15) * 128;  // q-block base (QBLK=128)
    const size_t base = (size_t)bh * (N_ * HD);
    const int q0w = q0 + w * 32;       // this wave's 32 q-cols

    // ---- hoist Q-side B-frags (loop-invariant): lane: q=l31, hd=kc*16+h*8
    bf16x8 bq[4], bqe[4];
#pragma unroll
    for (int kc = 0; kc < 4; ++kc) {
        int row = q0w + l31;
        int col = kc * 16 + h * 8;
        bq [kc] = *(const bf16x8*)(rq + base + (size_t)row * HD + col);
        bqe[kc] = *(const bf16x8*)(qf + base + (size_t)row * HD + col);
    }

    // ---- staging (6 x 16B per thread per ktile; pre-swizzled source chunk)
    uint4 st[6];
    {   // prologue: stage ktile 0
#pragma unroll
        for (int it = 0; it < 6; ++it) {
            int slot = it * 256 + t, ci = slot & 511, row = ci >> 3, cs = ci & 7;
            int cg = cs ^ (row & 7);
            const char* g;
            if (it < 2)      g = (const char*)(rk + base + (size_t)row * HD) + cg * 16;
            else if (it < 4) g = (const char*)(kf + base + (size_t)row * HD) + cg * 16;
            else             g = (const char*)(vt + base + (size_t)row * N_) + cg * 16;
            st[it] = *(const uint4*)g;
        }
#pragma unroll
        for (int it = 0; it < 6; ++it) {
            int slot = it * 256 + t, ci = slot & 511, row = ci >> 3, cs = ci & 7;
            *(uint4*)(sbuf[0] + (it >> 1) * 8192 + row * 128 + cs * 16) = st[it];
        }
    }
    __syncthreads();

    f32x16 o[2] = {};

    for (int kt = 0; kt < 32; ++kt) {
        const int cur = kt & 1;
        const char* Rk = sbuf[cur];
        const char* Ke = sbuf[cur] + 8192;
        const char* Vt = sbuf[cur] + 16384;

        // issue next tile's global loads early (latency hides under compute)
        if (kt + 1 < 32) {
            const int k0n = (kt + 1) * 64;
#pragma unroll
            for (int it = 0; it < 6; ++it) {
                int slot = it * 256 + t, ci = slot & 511, row = ci >> 3, cs = ci & 7;
                int cg = cs ^ (row & 7);
                const char* g;
                if (it < 2)      g = (const char*)(rk + base + (size_t)(k0n + row) * HD) + cg * 16;
                else if (it < 4) g = (const char*)(kf + base + (size_t)(k0n + row) * HD) + cg * 16;
                else             g = (const char*)(vt + base + (size_t)row * N_ + k0n) + cg * 16;
                st[it] = *(const uint4*)g;
            }
        }

        // ---- QK^T (swapped) + in-register W transform
        bf16x8 wa[4];
#pragma unroll
        for (int kb = 0; kb < 2; ++kb) {
            bf16x8 ark[4], ake[4];
#pragma unroll
            for (int kc = 0; kc < 4; ++kc) {
                ark[kc] = ldfrag(Rk, kb * 32 + l31, kc * 2 + h);
                ake[kc] = ldfrag(Ke, kb * 32 + l31, kc * 2 + h);
            }
            f32x16 num = {}, den = {};
#pragma unroll
            for (int kc = 0; kc < 4; ++kc)
                num = __builtin_amdgcn_mfma_f32_32x32x16_bf16(ark[kc], bq[kc], num, 0, 0, 0);
#pragma unroll
            for (int kc = 0; kc < 4; ++kc)
                den = __builtin_amdgcn_mfma_f32_32x32x16_bf16(ake[kc], bqe[kc], den, 0, 0, 0);
            // w = num/den; lane holds W^T[k_local][q=l31], k_local=(r&3)+8*(r>>2)+4*h
            unsigned u0 = pack2(num[0]  * __builtin_amdgcn_rcpf(den[0]),
                                num[1]  * __builtin_amdgcn_rcpf(den[1]));
            unsigned u1 = pack2(num[2]  * __builtin_amdgcn_rcpf(den[2]),
                                num[3]  * __builtin_amdgcn_rcpf(den[3]));
            unsigned u2 = pack2(num[4]  * __builtin_amdgcn_rcpf(den[4]),
                                num[5]  * __builtin_amdgcn_rcpf(den[5]));
            unsigned u3 = pack2(num[6]  * __builtin_amdgcn_rcpf(den[6]),
                                num[7]  * __builtin_amdgcn_rcpf(den[7]));
            unsigned u4 = pack2(num[8]  * __builtin_amdgcn_rcpf(den[8]),
                                num[9]  * __builtin_amdgcn_rcpf(den[9]));
            unsigned u5 = pack2(num[10] * __builtin_amdgcn_rcpf(den[10]),
                                num[11] * __builtin_amdgcn_rcpf(den[11]));
            unsigned u6 = pack2(num[12] * __builtin_amdgcn_rcpf(den[12]),
                                num[13] * __builtin_amdgcn_rcpf(den[13]));
            unsigned u7 = pack2(num[14] * __builtin_amdgcn_rcpf(den[14]),
                                num[15] * __builtin_amdgcn_rcpf(den[15]));
            // lane l <-> l+32 exchange (same q): builds A-frags W[q][k]
            asm volatile("v_permlane32_swap_b32 %0, %1" : "+v"(u0), "+v"(u2));
            asm volatile("v_permlane32_swap_b32 %0, %1" : "+v"(u1), "+v"(u3));
            asm volatile("v_permlane32_swap_b32 %0, %1" : "+v"(u4), "+v"(u6));
            asm volatile("v_permlane32_swap_b32 %0, %1" : "+v"(u5), "+v"(u7));
            union { unsigned uu[4]; bf16x8 v; } f0, f1;
            f0.uu[0] = u0; f0.uu[1] = u1; f0.uu[2] = u2; f0.uu[3] = u3;
            f1.uu[0] = u4; f1.uu[1] = u5; f1.uu[2] = u6; f1.uu[3] = u7;
            wa[kb * 2 + 0] = f0.v;
            wa[kb * 2 + 1] = f1.v;
        }

        // ---- PV: O[q][dv] += W @ V
#pragma unroll
        for (int db = 0; db < 2; ++db) {
            bf16x8 bv[4];
#pragma unroll
            for (int kc = 0; kc < 4; ++kc)
                bv[kc] = ldfrag(Vt, db * 32 + l31, kc * 2 + h);
#pragma unroll
            for (int kc = 0; kc < 4; ++kc)
                o[db] = __builtin_amdgcn_mfma_f32_32x32x16_bf16(wa[kc], bv[kc], o[db], 0, 0, 0);
        }

        // ---- write next tile to other buffer, then single barrier
        if (kt + 1 < 32) {
#pragma unroll
            for (int it = 0; it < 6; ++it) {
                int slot = it * 256 + t, ci = slot & 511, row = ci >> 3, cs = ci & 7;
                *(uint4*)(sbuf[cur ^ 1] + (it >> 1) * 8192 + row * 128 + cs * 16) = st[it];
            }
        }
        __syncthreads();
    }

    // epilogue: D-frag row q = (i&3)+8*(i>>2)+4*h, col dv = l31
#pragma unroll
    for (int db = 0; db < 2; ++db)
#pragma unroll
        for (int i = 0; i < 16; ++i) {
            int qq = q0w + (i & 3) + 8 * (i >> 2) + 4 * h;
            ctxb[base + (size_t)qq * HD + db * 32 + l31] = __float2bfloat16(o[db][i]);
        }
}

// ---------------------------------------------------------------- K3: out projection (MFMA)
__global__ __launch_bounds__(256) void k_proj(
        const __hip_bfloat16* __restrict__ ctxb, const __hip_bfloat16* __restrict__ woT,
        const float* __restrict__ bias, float* __restrict__ out) {
    __shared__ __align__(16) char sA[128 * 128];
    __shared__ __align__(16) char sB[128 * 128];

    const int t    = threadIdx.x;
    const int m0   = blockIdx.y * 128;
    const int n0w  = blockIdx.x * 128;
    const int lane = t & 63;
    const int lrow = lane & 15;
    const int lgrp = lane >> 4;
    const int wid  = t >> 6;
    const int wr   = wid >> 1;
    const int wc   = wid & 1;

    f32x4 acc[4][4] = {};

    for (int kt = 0; kt < D_ / 64; ++kt) {
        const int k0 = kt * 64;
        const int hh = k0 >> 6;
        __syncthreads();
#pragma unroll
        for (int it = 0; it < 4; ++it) {
            int slot = it * 256 + t;
            int r = slot >> 3, c = slot & 7;
            int m = m0 + r;
            int b = m >> 11, n = m & (N_ - 1);
            uint4 av = *(const uint4*)(ctxb + ((size_t)(b * H_ + hh) * N_ + n) * HD + c * 8);
            uint4 bv = *(const uint4*)(woT + (size_t)(n0w + r) * D_ + k0 + c * 8);
            stfrag16(sA, r, c, av);
            stfrag16(sB, r, c, bv);
        }
        __syncthreads();

        bf16x8 bfr[4][2];
#pragma unroll
        for (int fn = 0; fn < 4; ++fn) {
            bfr[fn][0] = ldfrag(sB, wc * 64 + fn * 16 + lrow, lgrp);
            bfr[fn][1] = ldfrag(sB, wc * 64 + fn * 16 + lrow, 4 + lgrp);
        }
#pragma unroll
        for (int fm = 0; fm < 4; ++fm) {
            bf16x8 a0 = ldfrag(sA, wr * 64 + fm * 16 + lrow, lgrp);
            bf16x8 a1 = ldfrag(sA, wr * 64 + fm * 16 + lrow, 4 + lgrp);
#pragma unroll
            for (int fn = 0; fn < 4; ++fn) {
                acc[fm][fn] = __builtin_amdgcn_mfma_f32_16x16x32_bf16(a0, bfr[fn][0], acc[fm][fn], 0, 0, 0);
                acc[fm][fn] = __builtin_amdgcn_mfma_f32_16x16x32_bf16(a1, bfr[fn][1], acc[fm][fn], 0, 0, 0);
            }
        }
    }

#pragma unroll
    for (int fn = 0; fn < 4; ++fn) {
        int c = n0w + wc * 64 + fn * 16 + lrow;
        float bia = bias[c];
#pragma unroll
        for (int fm = 0; fm < 4; ++fm) {
            int m = m0 + wr * 64 + fm * 16 + lgrp * 4;
#pragma unroll
            for (int r = 0; r < 4; ++r)
                out[(size_t)(m + r) * D_ + c] = acc[fm][fn][r] + bia;
        }
    }
}

// ---------------------------------------------------------------- launch
extern "C" void kernel_launch(void* const* d_in, const int* in_sizes, int n_in,
                              void* d_out, int out_size, void* d_ws, size_t ws_size,
                              hipStream_t stream) {
    const float* x     = (const float*)d_in[0];
    const float* w_qkv = (const float*)d_in[1];
    const float* b_qkv = (const float*)d_in[2];
    const float* w_out = (const float*)d_in[3];
    const float* b_out = (const float*)d_in[4];
    float* out = (float*)d_out;

    char* ws = (char*)d_ws;
    const size_t TAB  = (size_t)N_ * HALF * sizeof(float);      // 256 KB each
    const size_t HARR = (size_t)B_ * H_ * N_ * HD * 2;          // 8 MB bf16 each
    float* cos_t = (float*)ws;
    float* sin_t = (float*)(ws + TAB);
    char* p = ws + 2 * TAB;
    __hip_bfloat16* qf  = (__hip_bfloat16*)(p);            p += HARR;
    __hip_bfloat16* kf  = (__hip_bfloat16*)(p);            p += HARR;
    __hip_bfloat16* rq  = (__hip_bfloat16*)(p);            p += HARR;
    __hip_bfloat16* rk  = (__hip_bfloat16*)(p);            p += HARR;
    __hip_bfloat16* vt  = (__hip_bfloat16*)(p);            p += HARR;
    __hip_bfloat16* xb  = (__hip_bfloat16*)(p);            p += HARR;   // M_*D_ bf16 (8MB)
    __hip_bfloat16* ctxb = xb;      // ctx aliases xb (xb dead after k_qkv)
    __hip_bfloat16* wqT = (__hip_bfloat16*)(p);            p += (size_t)DQKV * D_ * 2;  // 6MB
    __hip_bfloat16* woT = (__hip_bfloat16*)(p);            p += (size_t)D_ * D_ * 2;    // 2MB

    hipLaunchKernelGGL(k_tables, dim3((N_ * HALF + 255) / 256), dim3(256), 0, stream,
                       cos_t, sin_t);
    hipLaunchKernelGGL(k_cvt_x, dim3(M_ * D_ / 4 / 256), dim3(256), 0, stream, x, xb);
    hipLaunchKernelGGL(k_cvt_t, dim3(DQKV / 32, D_ / 32), dim3(256), 0, stream,
                       w_qkv, wqT, DQKV);
    hipLaunchKernelGGL(k_cvt_t, dim3(D_ / 32, D_ / 32), dim3(256), 0, stream,
                       w_out, woT, D_);
    hipLaunchKernelGGL(k_qkv, dim3(DQKV / 128, M_ / 128), dim3(256), 0, stream,
                       xb, wqT, b_qkv, cos_t, sin_t, qf, kf, rq, rk, vt);
    hipLaunchKernelGGL(k_attn, dim3(512), dim3(256), 0, stream,
                       qf, kf, rq, rk, vt, ctxb);
    hipLaunchKernelGGL(k_proj, dim3(D_ / 128, M_ / 128), dim3(256), 0, stream,
                       ctxb, woT, b_out, out);
}

// Round 8
// 181.460 us; speedup vs baseline: 1.1394x; 1.1394x over previous
//
#include <hip/hip_runtime.h>
#include <hip/hip_bf16.h>

#define B_   2
#define N_   2048
#define D_   1024
#define H_   16
#define HD   64
#define HALF 32
#define M_   (B_*N_)     // 4096
#define DQKV (3*D_)      // 3072

typedef __bf16 bf16x8 __attribute__((ext_vector_type(8)));
typedef float  f32x4  __attribute__((ext_vector_type(4)));
typedef float  f32x16 __attribute__((ext_vector_type(16)));

// ---------------------------------------------------------------- swizzled LDS tile helpers
// tile: R rows x 64 bf16 (128B = 8 chunks of 16B per row)
// logical element (row, col) lives at byte row*128 + ((col>>3) ^ (row&7))*16 + (col&7)*2
__device__ __forceinline__ bf16x8 ldfrag(const char* tile, int row, int ch) {
    return *(const bf16x8*)(tile + row * 128 + (((ch) ^ (row & 7)) << 4));
}
__device__ __forceinline__ void stfrag16(char* tile, int row, int ch, uint4 v) {
    *(uint4*)(tile + row * 128 + (((ch) ^ (row & 7)) << 4)) = v;
}

__device__ __forceinline__ unsigned pack2(float a, float b) {
    union { __hip_bfloat16 h; unsigned short s; } x, y;
    x.h = __float2bfloat16(a); y.h = __float2bfloat16(b);
    return (unsigned)x.s | ((unsigned)y.s << 16);
}

// ---------------------------------------------------------------- K0: rope tables
__global__ __launch_bounds__(256) void k_tables(float* __restrict__ cos_t,
                                                float* __restrict__ sin_t) {
    int i = blockIdx.x * 256 + threadIdx.x;          // N_*HALF = 65536
    if (i >= N_ * HALF) return;
    int n = i / HALF, j = i % HALF;
    float theta = powf(10000.f, -(float)j / (float)HALF);
    float ang = (float)n * theta;
    cos_t[i] = cosf(ang);
    sin_t[i] = sinf(ang);
}

// ---------------------------------------------------------------- converts
__global__ __launch_bounds__(256) void k_cvt_x(const float* __restrict__ x,
                                               __hip_bfloat16* __restrict__ xb) {
    int i = blockIdx.x * 256 + threadIdx.x;          // over elems/4
    float4 v = ((const float4*)x)[i];
    union { ushort4 u; __hip_bfloat16 h[4]; } o;
    o.h[0] = __float2bfloat16(v.x); o.h[1] = __float2bfloat16(v.y);
    o.h[2] = __float2bfloat16(v.z); o.h[3] = __float2bfloat16(v.w);
    ((ushort4*)xb)[i] = o.u;
}

// transpose+convert: w (1024 x ncols, fp32) -> wt (ncols x 1024, bf16)
__global__ __launch_bounds__(256) void k_cvt_t(const float* __restrict__ w,
                                               __hip_bfloat16* __restrict__ wt, int ncols) {
    __shared__ float tile[32][33];
    int n0 = blockIdx.x * 32, k0 = blockIdx.y * 32;
    int tx = threadIdx.x & 31, ty = threadIdx.x >> 5;   // ty 0..7
#pragma unroll
    for (int i = 0; i < 32; i += 8)
        tile[ty + i][tx] = w[(size_t)(k0 + ty + i) * ncols + n0 + tx];
    __syncthreads();
#pragma unroll
    for (int i = 0; i < 32; i += 8)
        wt[(size_t)(n0 + ty + i) * 1024 + k0 + tx] = __float2bfloat16(tile[tx][ty + i]);
}

// ---------------------------------------------------------------- K1: QKV GEMM (MFMA) + elu+1 + rope
// (R6-proven reg-staged version)
__global__ __launch_bounds__(256) void k_qkv(
        const __hip_bfloat16* __restrict__ xb, const __hip_bfloat16* __restrict__ wqT,
        const float* __restrict__ bias,
        const float* __restrict__ cos_t, const float* __restrict__ sin_t,
        __hip_bfloat16* __restrict__ qf, __hip_bfloat16* __restrict__ kf,
        __hip_bfloat16* __restrict__ rq, __hip_bfloat16* __restrict__ rk,
        __hip_bfloat16* __restrict__ vt) {
    __shared__ __align__(16) char sA[128 * 128];   // 128 rows x 64 bf16
    __shared__ __align__(16) char sB[128 * 128];

    const int t    = threadIdx.x;
    const int m0   = blockIdx.y * 128;
    const int n0w  = blockIdx.x * 128;
    const int lane = t & 63;
    const int lrow = lane & 15;
    const int lgrp = lane >> 4;
    const int wid  = t >> 6;
    const int wr   = wid >> 1;          // wave row 0..1
    const int wc   = wid & 1;           // wave col 0..1

    f32x4 acc[4][4] = {};

    for (int kt = 0; kt < D_ / 64; ++kt) {
        const int k0 = kt * 64;
        __syncthreads();
#pragma unroll
        for (int it = 0; it < 4; ++it) {
            int slot = it * 256 + t;           // 0..1023
            int r = slot >> 3, c = slot & 7;
            uint4 av = *(const uint4*)(xb  + (size_t)(m0  + r) * D_ + k0 + c * 8);
            uint4 bv = *(const uint4*)(wqT + (size_t)(n0w + r) * D_ + k0 + c * 8);
            stfrag16(sA, r, c, av);
            stfrag16(sB, r, c, bv);
        }
        __syncthreads();

        bf16x8 bfr[4][2];
#pragma unroll
        for (int fn = 0; fn < 4; ++fn) {
            bfr[fn][0] = ldfrag(sB, wc * 64 + fn * 16 + lrow, lgrp);
            bfr[fn][1] = ldfrag(sB, wc * 64 + fn * 16 + lrow, 4 + lgrp);
        }
#pragma unroll
        for (int fm = 0; fm < 4; ++fm) {
            bf16x8 a0 = ldfrag(sA, wr * 64 + fm * 16 + lrow, lgrp);
            bf16x8 a1 = ldfrag(sA, wr * 64 + fm * 16 + lrow, 4 + lgrp);
#pragma unroll
            for (int fn = 0; fn < 4; ++fn) {
                acc[fm][fn] = __builtin_amdgcn_mfma_f32_16x16x32_bf16(a0, bfr[fn][0], acc[fm][fn], 0, 0, 0);
                acc[fm][fn] = __builtin_amdgcn_mfma_f32_16x16x32_bf16(a1, bfr[fn][1], acc[fm][fn], 0, 0, 0);
            }
        }
    }

#pragma unroll
    for (int fn = 0; fn < 4; ++fn) {
        int c   = n0w + wc * 64 + fn * 16 + lrow;
        int sec = c >> 10;
        int cc  = c & 1023;
        int h   = cc >> 6, dd = cc & 63;
        float bia = bias[c];
#pragma unroll
        for (int fm = 0; fm < 4; ++fm) {
            int mb = m0 + wr * 64 + fm * 16 + lgrp * 4;
            int b  = mb >> 11;
            int n  = mb & (N_ - 1);
            if (sec == 2) {
                union { ushort4 u; __hip_bfloat16 hh[4]; } pk;
#pragma unroll
                for (int r = 0; r < 4; ++r)
                    pk.hh[r] = __float2bfloat16(acc[fm][fn][r] + bia);
                *(ushort4*)(vt + ((size_t)(b * H_ + h) * HD + dd) * N_ + n) = pk.u;
            } else {
#pragma unroll
                for (int r = 0; r < 4; ++r) {
                    float val = acc[fm][fn][r] + bia;
                    float e  = val > 0.f ? val + 1.f : __expf(val);   // elu(x)+1
                    float ep = __shfl_xor(e, 1);
                    int pj = dd >> 1;
                    float cs = cos_t[(n + r) * HALF + pj];
                    float sn = sin_t[(n + r) * HALF + pj];
                    float rv = (dd & 1) ? (ep * sn + e * cs) : (e * cs - ep * sn);
                    size_t o = ((size_t)(b * H_ + h) * N_ + n + r) * HD + dd;
                    if (sec == 0) { qf[o] = __float2bfloat16(e); rq[o] = __float2bfloat16(rv); }
                    else          { kf[o] = __float2bfloat16(e); rk[o] = __float2bfloat16(rv); }
                }
            }
        }
    }
}

// ---------------------------------------------------------------- K2: fused linear attention
// R7 structure (512 thr = 4 q-waves x 2 k-splits, QBLK=256, grid 256 = 8 waves/CU)
// with R6-PROVEN reg staging: load-early (global uint4 at inverse-swz chunk) ->
// compute -> linear ds_write late -> one barrier per round. Per-ksplit double buffer.
// Swapped-operand 32x32x16 MFMA, in-register W transform (pack2+permlane32_swap).
__global__ __launch_bounds__(512, 2) void k_attn(
        const __hip_bfloat16* __restrict__ qf, const __hip_bfloat16* __restrict__ kf,
        const __hip_bfloat16* __restrict__ rq, const __hip_bfloat16* __restrict__ rk,
        const __hip_bfloat16* __restrict__ vt, __hip_bfloat16* __restrict__ ctxb) {
    __shared__ __align__(16) char sbuf[2][2][3 * 8192];   // [ksplit][dbuf][RK|KF|VT]

    const int t    = threadIdx.x;
    const int lane = t & 63;
    const int l31  = lane & 31;
    const int h    = lane >> 5;
    const int wid  = t >> 6;        // 0..7
    const int qw   = wid & 3;       // q-wave
    const int ks   = wid >> 2;      // k-split 0/1 (threads 0..255 = ks0, 256..511 = ks1)
    const int tl   = t & 255;       // thread within ks-half

    // XCD-chunked swizzle: 256 blocks; XCD x gets bh 4x..4x+3 (K/V ~3MB L2-resident)
    const int bid = blockIdx.x;
    const int swz = (bid & 7) * 32 + (bid >> 3);
    const int bh  = swz >> 3;           // 0..31
    const int q0  = (swz & 7) * 256;    // q-block base (QBLK=256)
    const size_t base = (size_t)bh * (N_ * HD);
    const int q0w = q0 + qw * 64;       // this wave's 64 q-cols

    // ---- hoist Q-side B-frags (loop-invariant): lane: q=l31, hd=kc*16+h*8
    bf16x8 bq[2][4], bqe[2][4];
#pragma unroll
    for (int qb = 0; qb < 2; ++qb)
#pragma unroll
        for (int kc = 0; kc < 4; ++kc) {
            int row = q0w + qb * 32 + l31;
            int col = kc * 16 + h * 8;
            bq [qb][kc] = *(const bf16x8*)(rq + base + (size_t)row * HD + col);
            bqe[qb][kc] = *(const bf16x8*)(qf + base + (size_t)row * HD + col);
        }

    // ---- staging: per ks-half 1536 slots (RK|KF|VT), 6 x 16B per thread.
    // slot s: tile=s>>9, row=(s&511)>>3, cs=s&7; holds global chunk cs^(row&7).
    uint4 st[6];
    auto stage_load = [&](int k0) {
#pragma unroll
        for (int j = 0; j < 6; ++j) {
            int slot = j * 256 + tl;
            int ci = slot & 511, tile = slot >> 9;   // tile uniform per j
            int row = ci >> 3, cs = ci & 7;
            int cg = cs ^ (row & 7);
            const char* g;
            if (tile == 0)      g = (const char*)(rk + base + (size_t)(k0 + row) * HD) + cg * 16;
            else if (tile == 1) g = (const char*)(kf + base + (size_t)(k0 + row) * HD) + cg * 16;
            else                g = (const char*)(vt + base + (size_t)row * N_ + k0) + cg * 16;
            st[j] = *(const uint4*)g;
        }
    };
    auto stage_write = [&](int buf) {
#pragma unroll
        for (int j = 0; j < 6; ++j) {
            int slot = j * 256 + tl;
            *(uint4*)(sbuf[ks][buf] + slot * 16) = st[j];
        }
    };

    stage_load(ks * 64);        // prologue: round 0 tile (kt = ks)
    stage_write(0);
    __syncthreads();

    f32x16 o[2][2] = {};

    for (int r = 0; r < 16; ++r) {
        const int cur = r & 1;
        const char* Rk = sbuf[ks][cur];
        const char* Ke = Rk + 8192;
        const char* Vt = Rk + 16384;

        if (r + 1 < 16) stage_load((2 * (r + 1) + ks) * 64);   // hide under compute

        // ---- QK^T (swapped) + in-register W transform
        bf16x8 wa[2][4];
#pragma unroll
        for (int kb = 0; kb < 2; ++kb) {
            bf16x8 ark[4], ake[4];
#pragma unroll
            for (int kc = 0; kc < 4; ++kc) {
                ark[kc] = ldfrag(Rk, kb * 32 + l31, kc * 2 + h);
                ake[kc] = ldfrag(Ke, kb * 32 + l31, kc * 2 + h);
            }
#pragma unroll
            for (int qb = 0; qb < 2; ++qb) {
                f32x16 num = {}, den = {};
#pragma unroll
                for (int kc = 0; kc < 4; ++kc)
                    num = __builtin_amdgcn_mfma_f32_32x32x16_bf16(ark[kc], bq[qb][kc], num, 0, 0, 0);
#pragma unroll
                for (int kc = 0; kc < 4; ++kc)
                    den = __builtin_amdgcn_mfma_f32_32x32x16_bf16(ake[kc], bqe[qb][kc], den, 0, 0, 0);
                // w = num/den; lane holds W^T[k_local][q=l31], k_local=(i&3)+8*(i>>2)+4*h
                unsigned u0 = pack2(num[0]  * __builtin_amdgcn_rcpf(den[0]),
                                    num[1]  * __builtin_amdgcn_rcpf(den[1]));
                unsigned u1 = pack2(num[2]  * __builtin_amdgcn_rcpf(den[2]),
                                    num[3]  * __builtin_amdgcn_rcpf(den[3]));
                unsigned u2 = pack2(num[4]  * __builtin_amdgcn_rcpf(den[4]),
                                    num[5]  * __builtin_amdgcn_rcpf(den[5]));
                unsigned u3 = pack2(num[6]  * __builtin_amdgcn_rcpf(den[6]),
                                    num[7]  * __builtin_amdgcn_rcpf(den[7]));
                unsigned u4 = pack2(num[8]  * __builtin_amdgcn_rcpf(den[8]),
                                    num[9]  * __builtin_amdgcn_rcpf(den[9]));
                unsigned u5 = pack2(num[10] * __builtin_amdgcn_rcpf(den[10]),
                                    num[11] * __builtin_amdgcn_rcpf(den[11]));
                unsigned u6 = pack2(num[12] * __builtin_amdgcn_rcpf(den[12]),
                                    num[13] * __builtin_amdgcn_rcpf(den[13]));
                unsigned u7 = pack2(num[14] * __builtin_amdgcn_rcpf(den[14]),
                                    num[15] * __builtin_amdgcn_rcpf(den[15]));
                // lane l <-> l+32 exchange (same q): builds A-frags W[q][k]
                asm volatile("v_permlane32_swap_b32 %0, %1" : "+v"(u0), "+v"(u2));
                asm volatile("v_permlane32_swap_b32 %0, %1" : "+v"(u1), "+v"(u3));
                asm volatile("v_permlane32_swap_b32 %0, %1" : "+v"(u4), "+v"(u6));
                asm volatile("v_permlane32_swap_b32 %0, %1" : "+v"(u5), "+v"(u7));
                union { unsigned uu[4]; bf16x8 v; } f0, f1;
                f0.uu[0] = u0; f0.uu[1] = u1; f0.uu[2] = u2; f0.uu[3] = u3;
                f1.uu[0] = u4; f1.uu[1] = u5; f1.uu[2] = u6; f1.uu[3] = u7;
                wa[qb][kb * 2 + 0] = f0.v;
                wa[qb][kb * 2 + 1] = f1.v;
            }
        }

        // ---- PV: O[q][dv] += W @ V
#pragma unroll
        for (int db = 0; db < 2; ++db) {
            bf16x8 bv[4];
#pragma unroll
            for (int kc = 0; kc < 4; ++kc)
                bv[kc] = ldfrag(Vt, db * 32 + l31, kc * 2 + h);
#pragma unroll
            for (int qb = 0; qb < 2; ++qb)
#pragma unroll
                for (int kc = 0; kc < 4; ++kc)
                    o[qb][db] = __builtin_amdgcn_mfma_f32_32x32x16_bf16(wa[qb][kc], bv[kc], o[qb][db], 0, 0, 0);
        }

        if (r + 1 < 16) stage_write(cur ^ 1);   // ds_write next tile to other buffer
        __syncthreads();                         // all writes visible; buffer reuse safe
    }

    // ---- k-split reduction (reuse sbuf as fp32 scratch, 64KB) + epilogue
    float* sred = (float*)sbuf;
    if (ks == 1) {
#pragma unroll
        for (int qb = 0; qb < 2; ++qb)
#pragma unroll
            for (int db = 0; db < 2; ++db)
#pragma unroll
                for (int i = 0; i < 16; ++i)
                    sred[(((qw * 2 + qb) * 2 + db) << 10) + i * 64 + lane] = o[qb][db][i];
    }
    __syncthreads();
    if (ks == 0) {
#pragma unroll
        for (int qb = 0; qb < 2; ++qb)
#pragma unroll
            for (int db = 0; db < 2; ++db)
#pragma unroll
                for (int i = 0; i < 16; ++i) {
                    float v = o[qb][db][i] + sred[(((qw * 2 + qb) * 2 + db) << 10) + i * 64 + lane];
                    int qq = q0w + qb * 32 + (i & 3) + 8 * (i >> 2) + 4 * h;
                    ctxb[base + (size_t)qq * HD + db * 32 + l31] = __float2bfloat16(v);
                }
    }
}

// ---------------------------------------------------------------- K3: out projection (MFMA)
// (R6-proven reg-staged version)
__global__ __launch_bounds__(256) void k_proj(
        const __hip_bfloat16* __restrict__ ctxb, const __hip_bfloat16* __restrict__ woT,
        const float* __restrict__ bias, float* __restrict__ out) {
    __shared__ __align__(16) char sA[128 * 128];
    __shared__ __align__(16) char sB[128 * 128];

    const int t    = threadIdx.x;
    const int m0   = blockIdx.y * 128;
    const int n0w  = blockIdx.x * 128;
    const int lane = t & 63;
    const int lrow = lane & 15;
    const int lgrp = lane >> 4;
    const int wid  = t >> 6;
    const int wr   = wid >> 1;
    const int wc   = wid & 1;

    f32x4 acc[4][4] = {};

    for (int kt = 0; kt < D_ / 64; ++kt) {
        const int k0 = kt * 64;
        const int hh = k0 >> 6;
        __syncthreads();
#pragma unroll
        for (int it = 0; it < 4; ++it) {
            int slot = it * 256 + t;
            int r = slot >> 3, c = slot & 7;
            int m = m0 + r;
            int b = m >> 11, n = m & (N_ - 1);
            uint4 av = *(const uint4*)(ctxb + ((size_t)(b * H_ + hh) * N_ + n) * HD + c * 8);
            uint4 bv = *(const uint4*)(woT + (size_t)(n0w + r) * D_ + k0 + c * 8);
            stfrag16(sA, r, c, av);
            stfrag16(sB, r, c, bv);
        }
        __syncthreads();

        bf16x8 bfr[4][2];
#pragma unroll
        for (int fn = 0; fn < 4; ++fn) {
            bfr[fn][0] = ldfrag(sB, wc * 64 + fn * 16 + lrow, lgrp);
            bfr[fn][1] = ldfrag(sB, wc * 64 + fn * 16 + lrow, 4 + lgrp);
        }
#pragma unroll
        for (int fm = 0; fm < 4; ++fm) {
            bf16x8 a0 = ldfrag(sA, wr * 64 + fm * 16 + lrow, lgrp);
            bf16x8 a1 = ldfrag(sA, wr * 64 + fm * 16 + lrow, 4 + lgrp);
#pragma unroll
            for (int fn = 0; fn < 4; ++fn) {
                acc[fm][fn] = __builtin_amdgcn_mfma_f32_16x16x32_bf16(a0, bfr[fn][0], acc[fm][fn], 0, 0, 0);
                acc[fm][fn] = __builtin_amdgcn_mfma_f32_16x16x32_bf16(a1, bfr[fn][1], acc[fm][fn], 0, 0, 0);
            }
        }
    }

#pragma unroll
    for (int fn = 0; fn < 4; ++fn) {
        int c = n0w + wc * 64 + fn * 16 + lrow;
        float bia = bias[c];
#pragma unroll
        for (int fm = 0; fm < 4; ++fm) {
            int m = m0 + wr * 64 + fm * 16 + lgrp * 4;
#pragma unroll
            for (int r = 0; r < 4; ++r)
                out[(size_t)(m + r) * D_ + c] = acc[fm][fn][r] + bia;
        }
    }
}

// ---------------------------------------------------------------- launch
extern "C" void kernel_launch(void* const* d_in, const int* in_sizes, int n_in,
                              void* d_out, int out_size, void* d_ws, size_t ws_size,
                              hipStream_t stream) {
    const float* x     = (const float*)d_in[0];
    const float* w_qkv = (const float*)d_in[1];
    const float* b_qkv = (const float*)d_in[2];
    const float* w_out = (const float*)d_in[3];
    const float* b_out = (const float*)d_in[4];
    float* out = (float*)d_out;

    char* ws = (char*)d_ws;
    const size_t TAB  = (size_t)N_ * HALF * sizeof(float);      // 256 KB each
    const size_t HARR = (size_t)B_ * H_ * N_ * HD * 2;          // 8 MB bf16 each
    float* cos_t = (float*)ws;
    float* sin_t = (float*)(ws + TAB);
    char* p = ws + 2 * TAB;
    __hip_bfloat16* qf  = (__hip_bfloat16*)(p);            p += HARR;
    __hip_bfloat16* kf  = (__hip_bfloat16*)(p);            p += HARR;
    __hip_bfloat16* rq  = (__hip_bfloat16*)(p);            p += HARR;
    __hip_bfloat16* rk  = (__hip_bfloat16*)(p);            p += HARR;
    __hip_bfloat16* vt  = (__hip_bfloat16*)(p);            p += HARR;
    __hip_bfloat16* xb  = (__hip_bfloat16*)(p);            p += HARR;   // M_*D_ bf16 (8MB)
    __hip_bfloat16* ctxb = xb;      // ctx aliases xb (xb dead after k_qkv)
    __hip_bfloat16* wqT = (__hip_bfloat16*)(p);            p += (size_t)DQKV * D_ * 2;  // 6MB
    __hip_bfloat16* woT = (__hip_bfloat16*)(p);            p += (size_t)D_ * D_ * 2;    // 2MB

    hipLaunchKernelGGL(k_tables, dim3((N_ * HALF + 255) / 256), dim3(256), 0, stream,
                       cos_t, sin_t);
    hipLaunchKernelGGL(k_cvt_x, dim3(M_ * D_ / 4 / 256), dim3(256), 0, stream, x, xb);
    hipLaunchKernelGGL(k_cvt_t, dim3(DQKV / 32, D_ / 32), dim3(256), 0, stream,
                       w_qkv, wqT, DQKV);
    hipLaunchKernelGGL(k_cvt_t, dim3(D_ / 32, D_ / 32), dim3(256), 0, stream,
                       w_out, woT, D_);
    hipLaunchKernelGGL(k_qkv, dim3(DQKV / 128, M_ / 128), dim3(256), 0, stream,
                       xb, wqT, b_qkv, cos_t, sin_t, qf, kf, rq, rk, vt);
    hipLaunchKernelGGL(k_attn, dim3(256), dim3(512), 0, stream,
                       qf, kf, rq, rk, vt, ctxb);
    hipLaunchKernelGGL(k_proj, dim3(D_ / 128, M_ / 128), dim3(256), 0, stream,
                       ctxb, woT, b_out, out);
}

// Round 10
// 178.006 us; speedup vs baseline: 1.1615x; 1.0194x over previous
//
#include <hip/hip_runtime.h>
#include <hip/hip_bf16.h>

#define B_   2
#define N_   2048
#define D_   1024
#define H_   16
#define HD   64
#define HALF 32
#define M_   (B_*N_)     // 4096
#define DQKV (3*D_)      // 3072

typedef __bf16 bf16x8 __attribute__((ext_vector_type(8)));
typedef float  f32x4  __attribute__((ext_vector_type(4)));
typedef float  f32x16 __attribute__((ext_vector_type(16)));

// ---------------------------------------------------------------- swizzled LDS tile helpers
// tile: R rows x 64 bf16 (128B = 8 chunks of 16B per row)
// logical element (row, col) lives at byte row*128 + ((col>>3) ^ (row&7))*16 + (col&7)*2
__device__ __forceinline__ bf16x8 ldfrag(const char* tile, int row, int ch) {
    return *(const bf16x8*)(tile + row * 128 + (((ch) ^ (row & 7)) << 4));
}
__device__ __forceinline__ void stfrag16(char* tile, int row, int ch, uint4 v) {
    *(uint4*)(tile + row * 128 + (((ch) ^ (row & 7)) << 4)) = v;
}

// async global->LDS DMA, 16B per lane; LDS dest = wave-uniform base + lane*16
__device__ __forceinline__ void gld16(const void* g, void* l) {
    __builtin_amdgcn_global_load_lds(
        (const __attribute__((address_space(1))) unsigned int*)g,
        (__attribute__((address_space(3))) unsigned int*)l, 16, 0, 0);
}

__device__ __forceinline__ unsigned pack2(float a, float b) {
    union { __hip_bfloat16 h; unsigned short s; } x, y;
    x.h = __float2bfloat16(a); y.h = __float2bfloat16(b);
    return (unsigned)x.s | ((unsigned)y.s << 16);
}

// ---------------------------------------------------------------- K0: rope tables
__global__ __launch_bounds__(256) void k_tables(float* __restrict__ cos_t,
                                                float* __restrict__ sin_t) {
    int i = blockIdx.x * 256 + threadIdx.x;          // N_*HALF = 65536
    if (i >= N_ * HALF) return;
    int n = i / HALF, j = i % HALF;
    float theta = powf(10000.f, -(float)j / (float)HALF);
    float ang = (float)n * theta;
    cos_t[i] = cosf(ang);
    sin_t[i] = sinf(ang);
}

// ---------------------------------------------------------------- converts
__global__ __launch_bounds__(256) void k_cvt_x(const float* __restrict__ x,
                                               __hip_bfloat16* __restrict__ xb) {
    int i = blockIdx.x * 256 + threadIdx.x;          // over elems/4
    float4 v = ((const float4*)x)[i];
    union { ushort4 u; __hip_bfloat16 h[4]; } o;
    o.h[0] = __float2bfloat16(v.x); o.h[1] = __float2bfloat16(v.y);
    o.h[2] = __float2bfloat16(v.z); o.h[3] = __float2bfloat16(v.w);
    ((ushort4*)xb)[i] = o.u;
}

// transpose+convert: w (1024 x ncols, fp32) -> wt (ncols x 1024, bf16)
__global__ __launch_bounds__(256) void k_cvt_t(const float* __restrict__ w,
                                               __hip_bfloat16* __restrict__ wt, int ncols) {
    __shared__ float tile[32][33];
    int n0 = blockIdx.x * 32, k0 = blockIdx.y * 32;
    int tx = threadIdx.x & 31, ty = threadIdx.x >> 5;   // ty 0..7
#pragma unroll
    for (int i = 0; i < 32; i += 8)
        tile[ty + i][tx] = w[(size_t)(k0 + ty + i) * ncols + n0 + tx];
    __syncthreads();
#pragma unroll
    for (int i = 0; i < 32; i += 8)
        wt[(size_t)(n0 + ty + i) * 1024 + k0 + tx] = __float2bfloat16(tile[tx][ty + i]);
}

// ---------------------------------------------------------------- K1: QKV GEMM (MFMA) + elu+1 + rope
// A/B this round: staging via global_load_lds (slot s=sb+lane: row=(sb>>3)+lr8,
// physical chunk lane&7 holds global chunk (lane&7)^(row&7); row&7==lr8 since sb%64==0).
__global__ __launch_bounds__(256) void k_qkv(
        const __hip_bfloat16* __restrict__ xb, const __hip_bfloat16* __restrict__ wqT,
        const float* __restrict__ bias,
        const float* __restrict__ cos_t, const float* __restrict__ sin_t,
        __hip_bfloat16* __restrict__ qf, __hip_bfloat16* __restrict__ kf,
        __hip_bfloat16* __restrict__ rq, __hip_bfloat16* __restrict__ rk,
        __hip_bfloat16* __restrict__ vt) {
    __shared__ __align__(16) char sA[128 * 128];   // 128 rows x 64 bf16
    __shared__ __align__(16) char sB[128 * 128];

    const int t    = threadIdx.x;
    const int m0   = blockIdx.y * 128;
    const int n0w  = blockIdx.x * 128;
    const int lane = t & 63;
    const int lrow = lane & 15;
    const int lgrp = lane >> 4;
    const int wid  = t >> 6;
    const int wr   = wid >> 1;          // wave row 0..1
    const int wc   = wid & 1;           // wave col 0..1
    const int lr8  = lane >> 3;         // 0..7
    const int cg   = (lane & 7) ^ lr8;  // inverse-swizzled source chunk

    f32x4 acc[4][4] = {};

    for (int kt = 0; kt < D_ / 64; ++kt) {
        const int k0 = kt * 64;
        __syncthreads();                 // prev compute done reading sA/sB
#pragma unroll
        for (int it = 0; it < 4; ++it) {
            int sb  = (wid * 4 + it) * 64;       // slot base (wave-uniform)
            int row = (sb >> 3) + lr8;           // per-lane row 0..127
            gld16(xb  + (size_t)(m0  + row) * D_ + k0 + cg * 8, sA + sb * 16);
            gld16(wqT + (size_t)(n0w + row) * D_ + k0 + cg * 8, sB + sb * 16);
        }
        __syncthreads();                 // drains vmcnt(0): tiles ready

        bf16x8 bfr[4][2];
#pragma unroll
        for (int fn = 0; fn < 4; ++fn) {
            bfr[fn][0] = ldfrag(sB, wc * 64 + fn * 16 + lrow, lgrp);
            bfr[fn][1] = ldfrag(sB, wc * 64 + fn * 16 + lrow, 4 + lgrp);
        }
#pragma unroll
        for (int fm = 0; fm < 4; ++fm) {
            bf16x8 a0 = ldfrag(sA, wr * 64 + fm * 16 + lrow, lgrp);
            bf16x8 a1 = ldfrag(sA, wr * 64 + fm * 16 + lrow, 4 + lgrp);
#pragma unroll
            for (int fn = 0; fn < 4; ++fn) {
                acc[fm][fn] = __builtin_amdgcn_mfma_f32_16x16x32_bf16(a0, bfr[fn][0], acc[fm][fn], 0, 0, 0);
                acc[fm][fn] = __builtin_amdgcn_mfma_f32_16x16x32_bf16(a1, bfr[fn][1], acc[fm][fn], 0, 0, 0);
            }
        }
    }

#pragma unroll
    for (int fn = 0; fn < 4; ++fn) {
        int c   = n0w + wc * 64 + fn * 16 + lrow;
        int sec = c >> 10;
        int cc  = c & 1023;
        int h   = cc >> 6, dd = cc & 63;
        float bia = bias[c];
#pragma unroll
        for (int fm = 0; fm < 4; ++fm) {
            int mb = m0 + wr * 64 + fm * 16 + lgrp * 4;
            int b  = mb >> 11;
            int n  = mb & (N_ - 1);
            if (sec == 2) {
                union { ushort4 u; __hip_bfloat16 hh[4]; } pk;
#pragma unroll
                for (int r = 0; r < 4; ++r)
                    pk.hh[r] = __float2bfloat16(acc[fm][fn][r] + bia);
                *(ushort4*)(vt + ((size_t)(b * H_ + h) * HD + dd) * N_ + n) = pk.u;
            } else {
#pragma unroll
                for (int r = 0; r < 4; ++r) {
                    float val = acc[fm][fn][r] + bia;
                    float e  = val > 0.f ? val + 1.f : __expf(val);   // elu(x)+1
                    float ep = __shfl_xor(e, 1);
                    int pj = dd >> 1;
                    float cs = cos_t[(n + r) * HALF + pj];
                    float sn = sin_t[(n + r) * HALF + pj];
                    float rv = (dd & 1) ? (ep * sn + e * cs) : (e * cs - ep * sn);
                    size_t o = ((size_t)(b * H_ + h) * N_ + n + r) * HD + dd;
                    if (sec == 0) { qf[o] = __float2bfloat16(e); rq[o] = __float2bfloat16(rv); }
                    else          { kf[o] = __float2bfloat16(e); rk[o] = __float2bfloat16(rv); }
                }
            }
        }
    }
}

// ---------------------------------------------------------------- K2: fused linear attention
// R8-EXACT (last known good): 512 thr = 4 q-waves x 2 k-splits, QBLK=256, grid 256.
// Reg staging, per-ksplit double buffer, swapped-operand 32x32x16 MFMA,
// in-register W transform (pack2+permlane32_swap). DO NOT EDIT without A/B.
__global__ __launch_bounds__(512, 2) void k_attn(
        const __hip_bfloat16* __restrict__ qf, const __hip_bfloat16* __restrict__ kf,
        const __hip_bfloat16* __restrict__ rq, const __hip_bfloat16* __restrict__ rk,
        const __hip_bfloat16* __restrict__ vt, __hip_bfloat16* __restrict__ ctxb) {
    __shared__ __align__(16) char sbuf[2][2][3 * 8192];   // [ksplit][dbuf][RK|KF|VT]

    const int t    = threadIdx.x;
    const int lane = t & 63;
    const int l31  = lane & 31;
    const int h    = lane >> 5;
    const int wid  = t >> 6;        // 0..7
    const int qw   = wid & 3;       // q-wave
    const int ks   = wid >> 2;      // k-split 0/1 (threads 0..255 = ks0, 256..511 = ks1)
    const int tl   = t & 255;       // thread within ks-half

    // XCD-chunked swizzle: 256 blocks; XCD x gets bh 4x..4x+3 (K/V ~3MB L2-resident)
    const int bid = blockIdx.x;
    const int swz = (bid & 7) * 32 + (bid >> 3);
    const int bh  = swz >> 3;           // 0..31
    const int q0  = (swz & 7) * 256;    // q-block base (QBLK=256)
    const size_t base = (size_t)bh * (N_ * HD);
    const int q0w = q0 + qw * 64;       // this wave's 64 q-cols

    // ---- hoist Q-side B-frags (loop-invariant): lane: q=l31, hd=kc*16+h*8
    bf16x8 bq[2][4], bqe[2][4];
#pragma unroll
    for (int qb = 0; qb < 2; ++qb)
#pragma unroll
        for (int kc = 0; kc < 4; ++kc) {
            int row = q0w + qb * 32 + l31;
            int col = kc * 16 + h * 8;
            bq [qb][kc] = *(const bf16x8*)(rq + base + (size_t)row * HD + col);
            bqe[qb][kc] = *(const bf16x8*)(qf + base + (size_t)row * HD + col);
        }

    // ---- staging: per ks-half 1536 slots (RK|KF|VT), 6 x 16B per thread.
    // slot s: tile=s>>9, row=(s&511)>>3, cs=s&7; holds global chunk cs^(row&7).
    uint4 st[6];
    auto stage_load = [&](int k0) {
#pragma unroll
        for (int j = 0; j < 6; ++j) {
            int slot = j * 256 + tl;
            int ci = slot & 511, tile = slot >> 9;   // tile uniform per j
            int row = ci >> 3, cs = ci & 7;
            int cg = cs ^ (row & 7);
            const char* g;
            if (tile == 0)      g = (const char*)(rk + base + (size_t)(k0 + row) * HD) + cg * 16;
            else if (tile == 1) g = (const char*)(kf + base + (size_t)(k0 + row) * HD) + cg * 16;
            else                g = (const char*)(vt + base + (size_t)row * N_ + k0) + cg * 16;
            st[j] = *(const uint4*)g;
        }
    };
    auto stage_write = [&](int buf) {
#pragma unroll
        for (int j = 0; j < 6; ++j) {
            int slot = j * 256 + tl;
            *(uint4*)(sbuf[ks][buf] + slot * 16) = st[j];
        }
    };

    stage_load(ks * 64);        // prologue: round 0 tile (kt = ks)
    stage_write(0);
    __syncthreads();

    f32x16 o[2][2] = {};

    for (int r = 0; r < 16; ++r) {
        const int cur = r & 1;
        const char* Rk = sbuf[ks][cur];
        const char* Ke = Rk + 8192;
        const char* Vt = Rk + 16384;

        if (r + 1 < 16) stage_load((2 * (r + 1) + ks) * 64);   // hide under compute

        // ---- QK^T (swapped) + in-register W transform
        bf16x8 wa[2][4];
#pragma unroll
        for (int kb = 0; kb < 2; ++kb) {
            bf16x8 ark[4], ake[4];
#pragma unroll
            for (int kc = 0; kc < 4; ++kc) {
                ark[kc] = ldfrag(Rk, kb * 32 + l31, kc * 2 + h);
                ake[kc] = ldfrag(Ke, kb * 32 + l31, kc * 2 + h);
            }
#pragma unroll
            for (int qb = 0; qb < 2; ++qb) {
                f32x16 num = {}, den = {};
#pragma unroll
                for (int kc = 0; kc < 4; ++kc)
                    num = __builtin_amdgcn_mfma_f32_32x32x16_bf16(ark[kc], bq[qb][kc], num, 0, 0, 0);
#pragma unroll
                for (int kc = 0; kc < 4; ++kc)
                    den = __builtin_amdgcn_mfma_f32_32x32x16_bf16(ake[kc], bqe[qb][kc], den, 0, 0, 0);
                // w = num/den; lane holds W^T[k_local][q=l31], k_local=(i&3)+8*(i>>2)+4*h
                unsigned u0 = pack2(num[0]  * __builtin_amdgcn_rcpf(den[0]),
                                    num[1]  * __builtin_amdgcn_rcpf(den[1]));
                unsigned u1 = pack2(num[2]  * __builtin_amdgcn_rcpf(den[2]),
                                    num[3]  * __builtin_amdgcn_rcpf(den[3]));
                unsigned u2 = pack2(num[4]  * __builtin_amdgcn_rcpf(den[4]),
                                    num[5]  * __builtin_amdgcn_rcpf(den[5]));
                unsigned u3 = pack2(num[6]  * __builtin_amdgcn_rcpf(den[6]),
                                    num[7]  * __builtin_amdgcn_rcpf(den[7]));
                unsigned u4 = pack2(num[8]  * __builtin_amdgcn_rcpf(den[8]),
                                    num[9]  * __builtin_amdgcn_rcpf(den[9]));
                unsigned u5 = pack2(num[10] * __builtin_amdgcn_rcpf(den[10]),
                                    num[11] * __builtin_amdgcn_rcpf(den[11]));
                unsigned u6 = pack2(num[12] * __builtin_amdgcn_rcpf(den[12]),
                                    num[13] * __builtin_amdgcn_rcpf(den[13]));
                unsigned u7 = pack2(num[14] * __builtin_amdgcn_rcpf(den[14]),
                                    num[15] * __builtin_amdgcn_rcpf(den[15]));
                // lane l <-> l+32 exchange (same q): builds A-frags W[q][k]
                asm volatile("v_permlane32_swap_b32 %0, %1" : "+v"(u0), "+v"(u2));
                asm volatile("v_permlane32_swap_b32 %0, %1" : "+v"(u1), "+v"(u3));
                asm volatile("v_permlane32_swap_b32 %0, %1" : "+v"(u4), "+v"(u6));
                asm volatile("v_permlane32_swap_b32 %0, %1" : "+v"(u5), "+v"(u7));
                union { unsigned uu[4]; bf16x8 v; } f0, f1;
                f0.uu[0] = u0; f0.uu[1] = u1; f0.uu[2] = u2; f0.uu[3] = u3;
                f1.uu[0] = u4; f1.uu[1] = u5; f1.uu[2] = u6; f1.uu[3] = u7;
                wa[qb][kb * 2 + 0] = f0.v;
                wa[qb][kb * 2 + 1] = f1.v;
            }
        }

        // ---- PV: O[q][dv] += W @ V
#pragma unroll
        for (int db = 0; db < 2; ++db) {
            bf16x8 bv[4];
#pragma unroll
            for (int kc = 0; kc < 4; ++kc)
                bv[kc] = ldfrag(Vt, db * 32 + l31, kc * 2 + h);
#pragma unroll
            for (int qb = 0; qb < 2; ++qb)
#pragma unroll
                for (int kc = 0; kc < 4; ++kc)
                    o[qb][db] = __builtin_amdgcn_mfma_f32_32x32x16_bf16(wa[qb][kc], bv[kc], o[qb][db], 0, 0, 0);
        }

        if (r + 1 < 16) stage_write(cur ^ 1);   // ds_write next tile to other buffer
        __syncthreads();                         // all writes visible; buffer reuse safe
    }

    // ---- k-split reduction (reuse sbuf as fp32 scratch, 64KB) + epilogue
    float* sred = (float*)sbuf;
    if (ks == 1) {
#pragma unroll
        for (int qb = 0; qb < 2; ++qb)
#pragma unroll
            for (int db = 0; db < 2; ++db)
#pragma unroll
                for (int i = 0; i < 16; ++i)
                    sred[(((qw * 2 + qb) * 2 + db) << 10) + i * 64 + lane] = o[qb][db][i];
    }
    __syncthreads();
    if (ks == 0) {
#pragma unroll
        for (int qb = 0; qb < 2; ++qb)
#pragma unroll
            for (int db = 0; db < 2; ++db)
#pragma unroll
                for (int i = 0; i < 16; ++i) {
                    float v = o[qb][db][i] + sred[(((qw * 2 + qb) * 2 + db) << 10) + i * 64 + lane];
                    int qq = q0w + qb * 32 + (i & 3) + 8 * (i >> 2) + 4 * h;
                    ctxb[base + (size_t)qq * HD + db * 32 + l31] = __float2bfloat16(v);
                }
    }
}

// ---------------------------------------------------------------- K3: out projection (MFMA)
// A/B this round: global_load_lds staging (same verified slot math as k_qkv).
__global__ __launch_bounds__(256) void k_proj(
        const __hip_bfloat16* __restrict__ ctxb, const __hip_bfloat16* __restrict__ woT,
        const float* __restrict__ bias, float* __restrict__ out) {
    __shared__ __align__(16) char sA[128 * 128];
    __shared__ __align__(16) char sB[128 * 128];

    const int t    = threadIdx.x;
    const int m0   = blockIdx.y * 128;
    const int n0w  = blockIdx.x * 128;
    const int lane = t & 63;
    const int lrow = lane & 15;
    const int lgrp = lane >> 4;
    const int wid  = t >> 6;
    const int wr   = wid >> 1;
    const int wc   = wid & 1;
    const int lr8  = lane >> 3;
    const int cg   = (lane & 7) ^ lr8;

    f32x4 acc[4][4] = {};

    for (int kt = 0; kt < D_ / 64; ++kt) {
        const int k0 = kt * 64;
        const int hh = k0 >> 6;
        __syncthreads();
#pragma unroll
        for (int it = 0; it < 4; ++it) {
            int sb  = (wid * 4 + it) * 64;
            int row = (sb >> 3) + lr8;
            int m = m0 + row;
            int b = m >> 11, n = m & (N_ - 1);
            gld16(ctxb + ((size_t)(b * H_ + hh) * N_ + n) * HD + cg * 8, sA + sb * 16);
            gld16(woT + (size_t)(n0w + row) * D_ + k0 + cg * 8, sB + sb * 16);
        }
        __syncthreads();

        bf16x8 bfr[4][2];
#pragma unroll
        for (int fn = 0; fn < 4; ++fn) {
            bfr[fn][0] = ldfrag(sB, wc * 64 + fn * 16 + lrow, lgrp);
            bfr[fn][1] = ldfrag(sB, wc * 64 + fn * 16 + lrow, 4 + lgrp);
        }
#pragma unroll
        for (int fm = 0; fm < 4; ++fm) {
            bf16x8 a0 = ldfrag(sA, wr * 64 + fm * 16 + lrow, lgrp);
            bf16x8 a1 = ldfrag(sA, wr * 64 + fm * 16 + lrow, 4 + lgrp);
#pragma unroll
            for (int fn = 0; fn < 4; ++fn) {
                acc[fm][fn] = __builtin_amdgcn_mfma_f32_16x16x32_bf16(a0, bfr[fn][0], acc[fm][fn], 0, 0, 0);
                acc[fm][fn] = __builtin_amdgcn_mfma_f32_16x16x32_bf16(a1, bfr[fn][1], acc[fm][fn], 0, 0, 0);
            }
        }
    }

#pragma unroll
    for (int fn = 0; fn < 4; ++fn) {
        int c = n0w + wc * 64 + fn * 16 + lrow;
        float bia = bias[c];
#pragma unroll
        for (int fm = 0; fm < 4; ++fm) {
            int m = m0 + wr * 64 + fm * 16 + lgrp * 4;
#pragma unroll
            for (int r = 0; r < 4; ++r)
                out[(size_t)(m + r) * D_ + c] = acc[fm][fn][r] + bia;
        }
    }
}

// ---------------------------------------------------------------- launch
extern "C" void kernel_launch(void* const* d_in, const int* in_sizes, int n_in,
                              void* d_out, int out_size, void* d_ws, size_t ws_size,
                              hipStream_t stream) {
    const float* x     = (const float*)d_in[0];
    const float* w_qkv = (const float*)d_in[1];
    const float* b_qkv = (const float*)d_in[2];
    const float* w_out = (const float*)d_in[3];
    const float* b_out = (const float*)d_in[4];
    float* out = (float*)d_out;

    char* ws = (char*)d_ws;
    const size_t TAB  = (size_t)N_ * HALF * sizeof(float);      // 256 KB each
    const size_t HARR = (size_t)B_ * H_ * N_ * HD * 2;          // 8 MB bf16 each
    float* cos_t = (float*)ws;
    float* sin_t = (float*)(ws + TAB);
    char* p = ws + 2 * TAB;
    __hip_bfloat16* qf  = (__hip_bfloat16*)(p);            p += HARR;
    __hip_bfloat16* kf  = (__hip_bfloat16*)(p);            p += HARR;
    __hip_bfloat16* rq  = (__hip_bfloat16*)(p);            p += HARR;
    __hip_bfloat16* rk  = (__hip_bfloat16*)(p);            p += HARR;
    __hip_bfloat16* vt  = (__hip_bfloat16*)(p);            p += HARR;
    __hip_bfloat16* xb  = (__hip_bfloat16*)(p);            p += HARR;   // M_*D_ bf16 (8MB)
    __hip_bfloat16* ctxb = xb;      // ctx aliases xb (xb dead after k_qkv)
    __hip_bfloat16* wqT = (__hip_bfloat16*)(p);            p += (size_t)DQKV * D_ * 2;  // 6MB
    __hip_bfloat16* woT = (__hip_bfloat16*)(p);            p += (size_t)D_ * D_ * 2;    // 2MB

    hipLaunchKernelGGL(k_tables, dim3((N_ * HALF + 255) / 256), dim3(256), 0, stream,
                       cos_t, sin_t);
    hipLaunchKernelGGL(k_cvt_x, dim3(M_ * D_ / 4 / 256), dim3(256), 0, stream, x, xb);
    hipLaunchKernelGGL(k_cvt_t, dim3(DQKV / 32, D_ / 32), dim3(256), 0, stream,
                       w_qkv, wqT, DQKV);
    hipLaunchKernelGGL(k_cvt_t, dim3(D_ / 32, D_ / 32), dim3(256), 0, stream,
                       w_out, woT, D_);
    hipLaunchKernelGGL(k_qkv, dim3(DQKV / 128, M_ / 128), dim3(256), 0, stream,
                       xb, wqT, b_qkv, cos_t, sin_t, qf, kf, rq, rk, vt);
    hipLaunchKernelGGL(k_attn, dim3(256), dim3(512), 0, stream,
                       qf, kf, rq, rk, vt, ctxb);
    hipLaunchKernelGGL(k_proj, dim3(D_ / 128, M_ / 128), dim3(256), 0, stream,
                       ctxb, woT, b_out, out);
}